// Round 3
// baseline (381.272 us; speedup 1.0000x reference)
//
#include <hip/hip_runtime.h>
#include <hip/hip_bf16.h>

typedef __attribute__((ext_vector_type(8))) short bf16x8;
typedef __attribute__((ext_vector_type(4))) float f32x4;

__device__ __forceinline__ unsigned short f2bf(float f) {
  union { __hip_bfloat16 b; unsigned short u; } cv;
  cv.b = __float2bfloat16(f);
  return cv.u;
}

// ---------------- K0: cast w2 (3072x128 f32) -> bf16 ----------------
__global__ __launch_bounds__(256) void k_cvt_w2(const float* __restrict__ w2,
                                                unsigned short* __restrict__ w2b) {
  const int i = (blockIdx.x * 256 + threadIdx.x) * 4;  // 98304 threads * 4 = 393216
  float4 v = *(const float4*)(w2 + i);
  union { uint2 u; unsigned short s[4]; } p;
  p.s[0] = f2bf(v.x); p.s[1] = f2bf(v.y); p.s[2] = f2bf(v.z); p.s[3] = f2bf(v.w);
  *(uint2*)(w2b + i) = p.u;
}

// ---------------- K1: conv(SAME,3x3)+mean-pool via boundary sums ----------------
// pooled[b,o] = conv_b[o] + (1/1024) * sum_i [ A*F + cR0*r0 + cR31*r31 + cC0*c0 + cC31*c31 + corners ]
__global__ __launch_bounds__(64) void k_convpool(const float* __restrict__ x,
                                                 const float* __restrict__ cw,
                                                 const float* __restrict__ cb,
                                                 float* __restrict__ pooled) {
  const int b = blockIdx.x;
  const int t = threadIdx.x;  // 0..63
  const float4* x4 = (const float4*)x + (size_t)b * 768;  // 3*1024/4
  float F[3] = {0,0,0}, R0[3] = {0,0,0}, R31[3] = {0,0,0}, C0[3] = {0,0,0}, C31[3] = {0,0,0};
  float k00[3] = {0,0,0}, k031[3] = {0,0,0}, k310[3] = {0,0,0}, k3131[3] = {0,0,0};
#pragma unroll
  for (int g = 0; g < 12; ++g) {
    const int i = g >> 2;               // channel
    const int p = (g & 3) * 64 + t;     // float4 index within channel, 0..255
    const int h = p >> 3;               // row 0..31
    const int wq = p & 7;               // float4-within-row 0..7
    float4 f = x4[g * 64 + t];
    float sm = f.x + f.y + f.z + f.w;
    F[i] += sm;
    if (h == 0)  R0[i]  += sm;
    if (h == 31) R31[i] += sm;
    if (wq == 0) C0[i]  += f.x;
    if (wq == 7) C31[i] += f.w;
    if (p == 0)   k00[i]   = f.x;   // x[0,0]
    if (p == 7)   k031[i]  = f.w;   // x[0,31]
    if (p == 248) k310[i]  = f.x;   // x[31,0]
    if (p == 255) k3131[i] = f.w;   // x[31,31]
  }
#pragma unroll
  for (int i = 0; i < 3; ++i) {
#pragma unroll
    for (int off = 32; off; off >>= 1) {
      F[i]   += __shfl_xor(F[i], off);
      R0[i]  += __shfl_xor(R0[i], off);
      R31[i] += __shfl_xor(R31[i], off);
      C0[i]  += __shfl_xor(C0[i], off);
      C31[i] += __shfl_xor(C31[i], off);
    }
    k00[i]   = __shfl(k00[i], 0);
    k031[i]  = __shfl(k031[i], 7);
    k310[i]  = __shfl(k310[i], 56);
    k3131[i] = __shfl(k3131[i], 63);
  }
  if (t < 4) {
    const int o = t;
    float acc = 0.f;
#pragma unroll
    for (int i = 0; i < 3; ++i) {
      const float* wp = cw + (o * 3 + i) * 9;
      float w00 = wp[0], w01 = wp[1], w02 = wp[2];
      float w10 = wp[3], w11 = wp[4], w12 = wp[5];
      float w20 = wp[6], w21 = wp[7], w22 = wp[8];
      acc += (w00 + w01 + w02 + w10 + w11 + w12 + w20 + w21 + w22) * F[i];
      acc -= (w20 + w21 + w22) * R0[i];    // dy=+1 excludes row 0
      acc -= (w00 + w01 + w02) * R31[i];   // dy=-1 excludes row 31
      acc -= (w02 + w12 + w22) * C0[i];    // dx=+1 excludes col 0
      acc -= (w00 + w10 + w20) * C31[i];   // dx=-1 excludes col 31
      acc += w00 * k3131[i] + w02 * k310[i] + w20 * k031[i] + w22 * k00[i];
    }
    pooled[b * 4 + o] = cb[o] + acc * (1.0f / 1024.0f);
  }
}

// ---------------- K2: quantum circuit + FC1 (one thread per batch row) ----------------
__global__ __launch_bounds__(256) void k_qnn(const float* __restrict__ pooled,
                                             const float* __restrict__ qw,
                                             const float* __restrict__ w1,
                                             const float* __restrict__ b1,
                                             unsigned short* __restrict__ hout) {
  const int b = blockIdx.x * 256 + threadIdx.x;
  float4 pv = *((const float4*)pooled + b);
  float c[4], s[4];
  {
    float th[4] = {pv.x * 0.5f, pv.y * 0.5f, pv.z * 0.5f, pv.w * 0.5f};
#pragma unroll
    for (int w = 0; w < 4; ++w) { s[w] = sinf(th[w]); c[w] = cosf(th[w]); }
  }
  float sr[16], si[16];
#pragma unroll
  for (int k = 0; k < 16; ++k) {
    sr[k] = (k & 8 ? s[0] : c[0]) * (k & 4 ? s[1] : c[1]) *
            (k & 2 ? s[2] : c[2]) * (k & 1 ? s[3] : c[3]);
    si[k] = 0.f;
  }
#pragma unroll
  for (int l = 0; l < 3; ++l) {
#pragma unroll
    for (int w = 0; w < 4; ++w) {
      float th = qw[l * 4 + w] * 0.5f;
      float cc = cosf(th), ss = sinf(th);
      const int m = 1 << (3 - w);
#pragma unroll
      for (int k = 0; k < 16; ++k) {
        if (!(k & m)) {
          const int kb = k | m;
          float ar = sr[k], ai = si[k], br = sr[kb], bi = si[kb];
          sr[k]  = cc * ar + ss * bi;
          si[k]  = cc * ai - ss * br;
          sr[kb] = cc * br + ss * ai;
          si[kb] = cc * bi - ss * ar;
        }
      }
    }
#pragma unroll
    for (int w = 0; w < 4; ++w) {
      const int mc = 1 << (3 - w);
      const int mt = 1 << (3 - ((w + 1) & 3));
#pragma unroll
      for (int k = 0; k < 16; ++k) {
        if ((k & mc) && !(k & mt)) {
          const int kb = k | mt;
          float tr = sr[k]; sr[k] = sr[kb]; sr[kb] = tr;
          float ti = si[k]; si[k] = si[kb]; si[kb] = ti;
        }
      }
    }
  }
  float q[4] = {0.f, 0.f, 0.f, 0.f};
#pragma unroll
  for (int k = 0; k < 16; ++k) {
    float pr = sr[k] * sr[k] + si[k] * si[k];
#pragma unroll
    for (int w = 0; w < 4; ++w) q[w] += (k & (1 << (3 - w))) ? -pr : pr;
  }
  // FC1: h[j] = relu(b1[j] + w1[j,:] . q), store bf16
#pragma unroll 1
  for (int jb = 0; jb < 16; ++jb) {
    union { uint4 u; unsigned short us[8]; } pack;
#pragma unroll
    for (int jj = 0; jj < 8; ++jj) {
      const int j = jb * 8 + jj;
      float4 wv = *((const float4*)w1 + j);
      float hv = b1[j] + wv.x * q[0] + wv.y * q[1] + wv.z * q[2] + wv.w * q[3];
      pack.us[jj] = f2bf(fmaxf(hv, 0.f));
    }
    ((uint4*)hout)[b * 16 + jb] = pack.u;
  }
}

// ---------------- K3: out = h @ w2^T + b2  (M=B, N=3072, K=128, bf16 MFMA) ----------------
__global__ __launch_bounds__(256) void k_gemm(const unsigned short* __restrict__ hA,  // [B][128]
                                              const unsigned short* __restrict__ w2b, // [3072][128]
                                              const float* __restrict__ b2,
                                              float* __restrict__ out) {
  const int bn = blockIdx.x * 64;
  const int bm = blockIdx.y * 64;
  const int t = threadIdx.x;
  const int lane = t & 63, wv = t >> 6;
  __shared__ unsigned short As[64][136];  // +8 bf16 pad breaks bank aliasing
  __shared__ unsigned short Bs[64][136];
  for (int cch = t; cch < 1024; cch += 256) {
    const int r = cch >> 4;
    const int col8 = (cch & 15) * 8;
    uint4 va = *(const uint4*)(hA + (size_t)(bm + r) * 128 + col8);
    *(uint4*)(&As[r][col8]) = va;
    uint4 vb = *(const uint4*)(w2b + (size_t)(bn + r) * 128 + col8);
    *(uint4*)(&Bs[r][col8]) = vb;
  }
  __syncthreads();
  f32x4 acc[4] = {{0,0,0,0},{0,0,0,0},{0,0,0,0},{0,0,0,0}};
  const int ar = wv * 16 + (lane & 15);
  const int kq = (lane >> 4) * 8;
#pragma unroll
  for (int ks = 0; ks < 4; ++ks) {
    bf16x8 a = *(const bf16x8*)(&As[ar][ks * 32 + kq]);
#pragma unroll
    for (int n = 0; n < 4; ++n) {
      bf16x8 bf = *(const bf16x8*)(&Bs[n * 16 + (lane & 15)][ks * 32 + kq]);
      acc[n] = __builtin_amdgcn_mfma_f32_16x16x32_bf16(a, bf, acc[n], 0, 0, 0);
    }
  }
  const int m0 = bm + wv * 16 + ((lane >> 4) << 2);
  const int c0 = bn + (lane & 15);
#pragma unroll
  for (int n = 0; n < 4; ++n) {
    const int col = c0 + n * 16;
    const float bias = b2[col];
#pragma unroll
    for (int j = 0; j < 4; ++j) {
      out[(size_t)(m0 + j) * 3072 + col] = acc[n][j] + bias;
    }
  }
}

extern "C" void kernel_launch(void* const* d_in, const int* in_sizes, int n_in,
                              void* d_out, int out_size, void* d_ws, size_t ws_size,
                              hipStream_t stream) {
  const float* x      = (const float*)d_in[0];
  const float* conv_w = (const float*)d_in[1];
  const float* conv_b = (const float*)d_in[2];
  const float* qw     = (const float*)d_in[3];
  const float* w1     = (const float*)d_in[4];
  const float* b1     = (const float*)d_in[5];
  const float* w2     = (const float*)d_in[6];
  const float* b2     = (const float*)d_in[7];
  float* out = (float*)d_out;

  const int B = in_sizes[0] / 3072;  // 16384

  char* ws = (char*)d_ws;
  float* pooled        = (float*)ws;                                  // B*4*4 bytes
  unsigned short* hbf  = (unsigned short*)(ws + (size_t)B * 16);      // B*128*2 bytes
  unsigned short* w2b  = (unsigned short*)(ws + (size_t)B * 16 + (size_t)B * 256);  // 786432 bytes

  hipLaunchKernelGGL(k_cvt_w2, dim3(384), dim3(256), 0, stream, w2, w2b);
  hipLaunchKernelGGL(k_convpool, dim3(B), dim3(64), 0, stream, x, conv_w, conv_b, pooled);
  hipLaunchKernelGGL(k_qnn, dim3(B / 256), dim3(256), 0, stream, pooled, qw, w1, b1, hbf);
  hipLaunchKernelGGL(k_gemm, dim3(48, B / 64), dim3(256), 0, stream, hbf, w2b, b2, out);
}